// Round 8
// baseline (111.878 us; speedup 1.0000x reference)
//
#include <hip/hip_runtime.h>
#include <math.h>
#include <stdint.h>

// NoisyTopKGating: B=4, S=4096, D=2048, E=64, K=2
#define D_ 2048
#define E_ 64
#define T_ 16384

#define BM 64                // tokens per block
#define KTILES 32            // D_/64
#define BTILE_B 49152        // 48 frag-rows x 1024 B = 48 KB per buffer
#define CT_STRIDE 132        // fp32 C tile stride (epilogue)

typedef __attribute__((ext_vector_type(8))) short s8v;   // 8 bf16 (4 VGPR)
typedef __attribute__((ext_vector_type(4))) float f4v;   // MFMA acc

__device__ __forceinline__ unsigned short bf16_rne(float f) {
    union { float f; uint32_t u; } c; c.f = f;
    return (unsigned short)((c.u + 0x7FFFu + ((c.u >> 16) & 1u)) >> 16);
}
__device__ __forceinline__ float bf16_tof(unsigned short b) {
    union { uint32_t u; float f; } c; c.u = ((uint32_t)b) << 16;
    return c.f;
}

// in-register 3-way truncation split of 8 f32 -> 3 bf16x8 planes
__device__ __forceinline__ void split3(const float4& a, const float4& b,
                                       s8v& h, s8v& m, s8v& l) {
    const float xe[8] = {a.x, a.y, a.z, a.w, b.x, b.y, b.z, b.w};
#pragma unroll
    for (int i = 0; i < 8; ++i) {
        union { float f; uint32_t u; } c; c.f = xe[i];
        h[i] = (short)(c.u >> 16);
        union { uint32_t u; float f; } t; t.u = c.u & 0xFFFF0000u;
        const float r1 = xe[i] - t.f;
        union { float f; uint32_t u; } c1; c1.f = r1;
        m[i] = (short)(c1.u >> 16);
        union { uint32_t u; float f; } t1; t1.u = c1.u & 0xFFFF0000u;
        const float r2 = r1 - t1.f;
        union { float f; uint32_t u; } c2; c2.f = r2;
        l[i] = (short)(c2.u >> 16);
    }
}

// ================= per-token noisy top-2 epilogue (shared) ==================
__device__ __forceinline__ void topk_epilogue(float g, float nl, float nz,
                                              int lane, size_t tg,
                                              float* __restrict__ out_probs,
                                              float* __restrict__ out_idx) {
    // softplus(z) = max(z,0) + log1p(exp(-|z|))
    const float sp = fmaxf(nl, 0.f) + log1pf(expf(-fabsf(nl)));
    const float noisy = g + nz * sp;

    float v = noisy;
    int idx = lane;
#pragma unroll
    for (int off = 32; off > 0; off >>= 1) {
        const float ov = __shfl_xor(v, off);
        const int oi = __shfl_xor(idx, off);
        if (ov > v || (ov == v && oi < idx)) { v = ov; idx = oi; }
    }
    const float v1 = v;
    const int i1 = idx;
    v = (lane == i1) ? -INFINITY : noisy;
    idx = lane;
#pragma unroll
    for (int off = 32; off > 0; off >>= 1) {
        const float ov = __shfl_xor(v, off);
        const int oi = __shfl_xor(idx, off);
        if (ov > v || (ov == v && oi < idx)) { v = ov; idx = oi; }
    }
    const float v2 = v;
    const int i2 = idx;

    const float e2 = expf(v2 - v1);
    const float denom = 1.f + e2;
    const float p = (lane == i1) ? (1.f / denom)
                                 : ((lane == i2) ? (e2 / denom) : 0.f);
    out_probs[tg * E_ + lane] = p;
    if (lane == 0) {
        out_idx[tg * 2 + 0] = (float)i1;
        out_idx[tg * 2 + 1] = (float)i2;
    }
}

// ---------------- kernel 1: pre-split W = [Wg;Wn] into 3 bf16 planes --------
// Frag-linear layout: plane p, n-frag f(8), k-step s(64), lane(64) -> 8 bf16.
// b-frag semantics: n = f*16 + (lane&15), k = s*32 + (lane>>4)*8 + i.
__global__ void w_split_kernel(const float* __restrict__ Wg,
                               const float* __restrict__ Wn,
                               unsigned short* __restrict__ wsp) {
    const int idx = blockIdx.x * blockDim.x + threadIdx.x;  // 0..32767
    const int lane = idx & 63;
    const int s = (idx >> 6) & 63;
    const int f = idx >> 12;
    const int n = f * 16 + (lane & 15);
    const int k0 = s * 32 + ((lane >> 4) << 3);
    const float* src = (n < 64) ? &Wg[(size_t)n * D_ + k0]
                                : &Wn[(size_t)(n - 64) * D_ + k0];
    s8v hv, mv, lv;
#pragma unroll
    for (int i = 0; i < 8; ++i) {
        const float f0 = src[i];
        const unsigned short hb = bf16_rne(f0);
        const float r1 = f0 - bf16_tof(hb);
        const unsigned short mb = bf16_rne(r1);
        const unsigned short lb = bf16_rne(r1 - bf16_tof(mb));
        hv[i] = (short)hb; mv[i] = (short)mb; lv[i] = (short)lb;
    }
    s8v* out = (s8v*)wsp;
    const int PLANE_FRAGS = 8 * 64 * 64;  // 32768 frags of 16 B per plane
    out[0 * PLANE_FRAGS + idx] = hv;
    out[1 * PLANE_FRAGS + idx] = mv;
    out[2 * PLANE_FRAGS + idx] = lv;
}

// ---------------- kernel 2: fused split-bf16 MFMA GEMM + noisy top-2 --------
// 1024 threads = 16 waves (4m x 4n), BM=64, grid=256.
// A: direct global f32 loads + in-register split (no LDS for A).
// B: reg-staged into double-buffered LDS (48 KB x2), 1 barrier per K-tile.
__launch_bounds__(1024)
__global__ void gemm_topk_kernel(const float* __restrict__ x,
                                 const unsigned short* __restrict__ wsp,
                                 const float* __restrict__ bg,
                                 const float* __restrict__ bn,
                                 const float* __restrict__ noise,
                                 float* __restrict__ out_probs,
                                 float* __restrict__ out_idx) {
    __shared__ __align__(16) char smem[2 * BTILE_B];  // 96 KB
    const int tid = threadIdx.x;
    const int lane = tid & 63;
    const int wv = tid >> 6;           // 0..15
    const int wm = wv >> 2;            // m-frag (16 rows)
    const int wn = wv & 3;             // n-quadrant (2 frags of 16 cols)
    const int block_m0 = blockIdx.x * BM;

    // A addressing: row = wm*16 + (lane&15); k = t*64 + ss*32 + (lane>>4)*8 + i
    const int arow = lane & 15;
    const int akg = lane >> 4;
    const float* xp = x + (size_t)(block_m0 + wm * 16 + arow) * D_ + akg * 8;

    // B staging: 48 frag-rows (p,f,ss) of 1 KB; this thread owns 3.
    // sidx -> p = sidx>>4, f = (sidx&15)>>1, ss = sidx&1
    const char* wb = (const char*)wsp;
    const int s0 = wv * 3 + 0, s1 = wv * 3 + 1, s2 = wv * 3 + 2;
#define GOFF(sidx) ((size_t)((((sidx) >> 4) * 8 + (((sidx) & 15) >> 1)) * 4096 + \
                             ((sidx) & 1) * 64 + lane) * 16)
    const size_t g0 = GOFF(s0), g1 = GOFF(s1), g2 = GOFF(s2);
#undef GOFF
    const int l0 = s0 * 1024 + lane * 16;
    const int l1 = s1 * 1024 + lane * 16;
    const int l2 = s2 * 1024 + lane * 16;

    // B compute-read offset: (p*16 + (wn*2+nf)*2 + ss)*1024 + lane*16
    const int rb = lane * 16;
#define ROFF(p, nf, ss) (((p) * 16 + (wn * 2 + (nf)) * 2 + (ss)) * 1024 + rb)

    f4v acc0{}, acc1{};   // nf = 0, 1

    // ---- prologue: stage tile 0 into buf0 ----
    {
        const s8v p0 = *(const s8v*)(wb + g0);
        const s8v p1 = *(const s8v*)(wb + g1);
        const s8v p2 = *(const s8v*)(wb + g2);
        *(s8v*)(smem + l0) = p0;
        *(s8v*)(smem + l1) = p1;
        *(s8v*)(smem + l2) = p2;
    }
    __syncthreads();

    int cur = 0;
#pragma unroll 1
    for (int t = 0; t < KTILES; ++t) {
        // issue next-tile B loads early (latency hides under this tile's work)
        const size_t tb = (size_t)((t + 1 < KTILES) ? t + 1 : t) * 2048;
        const s8v st0 = *(const s8v*)(wb + g0 + tb);
        const s8v st1 = *(const s8v*)(wb + g1 + tb);
        const s8v st2 = *(const s8v*)(wb + g2 + tb);

        // A: load 16 f32 (both k-steps), split in registers
        const float4 a00 = *(const float4*)(xp + t * 64);
        const float4 a01 = *(const float4*)(xp + t * 64 + 4);
        const float4 a10 = *(const float4*)(xp + t * 64 + 32);
        const float4 a11 = *(const float4*)(xp + t * 64 + 36);
        s8v xh0, xm0, xl0, xh1, xm1, xl1;
        split3(a00, a01, xh0, xm0, xl0);
        split3(a10, a11, xh1, xm1, xl1);

        const char* buf = smem + cur * BTILE_B;
#define MFMA_(A, Bf, C) C = __builtin_amdgcn_mfma_f32_16x16x32_bf16(A, Bf, C, 0, 0, 0)
        {   // ss = 0
            const s8v bh0 = *(const s8v*)(buf + ROFF(0, 0, 0));
            const s8v bh1 = *(const s8v*)(buf + ROFF(0, 1, 0));
            const s8v bm0 = *(const s8v*)(buf + ROFF(1, 0, 0));
            const s8v bm1 = *(const s8v*)(buf + ROFF(1, 1, 0));
            const s8v bl0 = *(const s8v*)(buf + ROFF(2, 0, 0));
            const s8v bl1 = *(const s8v*)(buf + ROFF(2, 1, 0));
            MFMA_(xh0, bh0, acc0); MFMA_(xh0, bh1, acc1);   // hi*hi
            MFMA_(xh0, bm0, acc0); MFMA_(xh0, bm1, acc1);   // hi*mid
            MFMA_(xm0, bh0, acc0); MFMA_(xm0, bh1, acc1);   // mid*hi
            MFMA_(xh0, bl0, acc0); MFMA_(xh0, bl1, acc1);   // hi*lo
            MFMA_(xm0, bm0, acc0); MFMA_(xm0, bm1, acc1);   // mid*mid
            MFMA_(xl0, bh0, acc0); MFMA_(xl0, bh1, acc1);   // lo*hi
        }
        {   // ss = 1
            const s8v bh0 = *(const s8v*)(buf + ROFF(0, 0, 1));
            const s8v bh1 = *(const s8v*)(buf + ROFF(0, 1, 1));
            const s8v bm0 = *(const s8v*)(buf + ROFF(1, 0, 1));
            const s8v bm1 = *(const s8v*)(buf + ROFF(1, 1, 1));
            const s8v bl0 = *(const s8v*)(buf + ROFF(2, 0, 1));
            const s8v bl1 = *(const s8v*)(buf + ROFF(2, 1, 1));
            MFMA_(xh1, bh0, acc0); MFMA_(xh1, bh1, acc1);
            MFMA_(xh1, bm0, acc0); MFMA_(xh1, bm1, acc1);
            MFMA_(xm1, bh0, acc0); MFMA_(xm1, bh1, acc1);
            MFMA_(xh1, bl0, acc0); MFMA_(xh1, bl1, acc1);
            MFMA_(xm1, bm0, acc0); MFMA_(xm1, bm1, acc1);
            MFMA_(xl1, bh0, acc0); MFMA_(xl1, bh1, acc1);
        }
#undef MFMA_
#undef ROFF
        // write staged B into the other buffer (T14 write-late)
        char* nbuf = smem + (cur ^ 1) * BTILE_B;
        *(s8v*)(nbuf + l0) = st0;
        *(s8v*)(nbuf + l1) = st1;
        *(s8v*)(nbuf + l2) = st2;
        __syncthreads();
        cur ^= 1;
    }

    // ---- epilogue: C tile to LDS (fp32), then per-token noisy top-2 ----
    float* Ct = (float*)smem;  // [64][CT_STRIDE] = 33792 B, fits in smem
    {
        const int ko4 = akg * 4;
#pragma unroll
        for (int r = 0; r < 4; ++r) {
            const int row = wm * 16 + ko4 + r;
            Ct[row * CT_STRIDE + wn * 32 + 0 * 16 + arow] = acc0[r];
            Ct[row * CT_STRIDE + wn * 32 + 1 * 16 + arow] = acc1[r];
        }
    }
    __syncthreads();

    const float my_bg = bg[lane];
    const float my_bn = bn[lane];
#pragma unroll 1
    for (int tt = 0; tt < 4; ++tt) {
        const int tl = wv * 4 + tt;
        const size_t tg = (size_t)block_m0 + tl;
        const float g = Ct[tl * CT_STRIDE + lane] + my_bg;
        const float nl = Ct[tl * CT_STRIDE + 64 + lane] + my_bn;
        const float nz = noise[tg * E_ + lane];
        topk_epilogue(g, nl, nz, lane, tg, out_probs, out_idx);
    }
}

// ---------------- fallback: pure-f32 fused kernel (no ws) -------------------
#define FBM 64
#define FBK 32
#define XS_STRIDE 68
#define WS_STRIDE 132
#define FCT_STRIDE 132

__launch_bounds__(256)
__global__ void noisy_topk_f32_kernel(const float* __restrict__ x,
                                      const float* __restrict__ Wg,
                                      const float* __restrict__ bg,
                                      const float* __restrict__ Wn,
                                      const float* __restrict__ bn,
                                      const float* __restrict__ noise,
                                      float* __restrict__ out_probs,
                                      float* __restrict__ out_idx) {
    __shared__ float smem[FBM * FCT_STRIDE];
    float* Xs = smem;
    float* Ws = smem + FBK * XS_STRIDE;

    const int tid = threadIdx.x;
    const int block_m0 = blockIdx.x * FBM;
    const int n0 = (tid & 31) * 4;
    const int m0 = (tid >> 5) * 8;

    float acc[8][4];
#pragma unroll
    for (int i = 0; i < 8; ++i)
#pragma unroll
        for (int j = 0; j < 4; ++j) acc[i][j] = 0.f;

    const int sj = tid & 7;
    const int sr = tid >> 3;

    for (int k0 = 0; k0 < D_; k0 += FBK) {
        __syncthreads();
#pragma unroll
        for (int it = 0; it < 2; ++it) {
            const int m = sr + it * 32;
            const float4 v = *reinterpret_cast<const float4*>(
                &x[(size_t)(block_m0 + m) * D_ + k0 + 4 * sj]);
            Xs[(4 * sj + 0) * XS_STRIDE + m] = v.x;
            Xs[(4 * sj + 1) * XS_STRIDE + m] = v.y;
            Xs[(4 * sj + 2) * XS_STRIDE + m] = v.z;
            Xs[(4 * sj + 3) * XS_STRIDE + m] = v.w;
        }
#pragma unroll
        for (int it = 0; it < 4; ++it) {
            const int n = sr + it * 32;
            const float* wrow = (n < 64) ? &Wg[(size_t)n * D_] : &Wn[(size_t)(n - 64) * D_];
            const float4 v = *reinterpret_cast<const float4*>(&wrow[k0 + 4 * sj]);
            Ws[(4 * sj + 0) * WS_STRIDE + n] = v.x;
            Ws[(4 * sj + 1) * WS_STRIDE + n] = v.y;
            Ws[(4 * sj + 2) * WS_STRIDE + n] = v.z;
            Ws[(4 * sj + 3) * WS_STRIDE + n] = v.w;
        }
        __syncthreads();
#pragma unroll
        for (int k = 0; k < FBK; ++k) {
            const float4 a0 = *reinterpret_cast<const float4*>(&Xs[k * XS_STRIDE + m0]);
            const float4 a1 = *reinterpret_cast<const float4*>(&Xs[k * XS_STRIDE + m0 + 4]);
            const float4 b4 = *reinterpret_cast<const float4*>(&Ws[k * WS_STRIDE + n0]);
            const float am[8] = {a0.x, a0.y, a0.z, a0.w, a1.x, a1.y, a1.z, a1.w};
            const float bb[4] = {b4.x, b4.y, b4.z, b4.w};
#pragma unroll
            for (int i = 0; i < 8; ++i)
#pragma unroll
                for (int j = 0; j < 4; ++j)
                    acc[i][j] = fmaf(am[i], bb[j], acc[i][j]);
        }
    }

    __syncthreads();
    float* Ct = smem;
#pragma unroll
    for (int i = 0; i < 8; ++i)
#pragma unroll
        for (int j = 0; j < 4; ++j)
            Ct[(m0 + i) * FCT_STRIDE + n0 + j] = acc[i][j];
    __syncthreads();

    const int wave = tid >> 6;
    const int lane = tid & 63;
    const float my_bg = bg[lane];
    const float my_bn = bn[lane];
#pragma unroll 1
    for (int tt = 0; tt < 16; ++tt) {
        const int tl = wave * 16 + tt;
        const size_t tg = (size_t)block_m0 + tl;
        const float g = Ct[tl * FCT_STRIDE + lane] + my_bg;
        const float nl = Ct[tl * FCT_STRIDE + 64 + lane] + my_bn;
        const float nz = noise[tg * E_ + lane];
        topk_epilogue(g, nl, nz, lane, tg, out_probs, out_idx);
    }
}

extern "C" void kernel_launch(void* const* d_in, const int* in_sizes, int n_in,
                              void* d_out, int out_size, void* d_ws, size_t ws_size,
                              hipStream_t stream) {
    const float* x = (const float*)d_in[0];
    const float* Wg = (const float*)d_in[1];
    const float* bg = (const float*)d_in[2];
    const float* Wn = (const float*)d_in[3];
    const float* bn = (const float*)d_in[4];
    const float* noise = (const float*)d_in[5];
    float* out_probs = (float*)d_out;
    float* out_idx = out_probs + (size_t)T_ * E_;

    const size_t WSP_BYTES = (size_t)3 * 32768 * 16;  // 1.57 MB
    if (ws_size >= WSP_BYTES) {
        unsigned short* wsp = (unsigned short*)d_ws;
        hipLaunchKernelGGL(w_split_kernel, dim3(128), dim3(256), 0, stream, Wg, Wn, wsp);
        hipLaunchKernelGGL(gemm_topk_kernel, dim3(T_ / BM), dim3(1024), 0, stream,
                           x, wsp, bg, bn, noise, out_probs, out_idx);
    } else {
        hipLaunchKernelGGL(noisy_topk_f32_kernel, dim3(T_ / FBM), dim3(256), 0, stream,
                           x, Wg, bg, Wn, bn, noise, out_probs, out_idx);
    }
}

// Round 9
// 92.123 us; speedup vs baseline: 1.2144x; 1.2144x over previous
//
#include <hip/hip_runtime.h>
#include <math.h>
#include <stdint.h>

// NoisyTopKGating: B=4, S=4096, D=2048, E=64, K=2
#define D_ 2048
#define E_ 64
#define T_ 16384

#define BM 64                 // tokens per block
#define BK 32                 // k per tile
#define KTILES (D_ / BK)      // 64
#define ABUF_B 8192           // 64 rows x 128 B (f32 x-tile)
#define BBUF_B 24576          // 24 frag-rows x 1024 B (split-W tile)
#define CT_STRIDE 132         // fp32 C tile stride (epilogue)

typedef __attribute__((ext_vector_type(8))) short s8v;   // 8 bf16 (4 VGPR)
typedef __attribute__((ext_vector_type(4))) float f4v;   // MFMA acc

__device__ __forceinline__ unsigned short bf16_rne(float f) {
    union { float f; uint32_t u; } c; c.f = f;
    return (unsigned short)((c.u + 0x7FFFu + ((c.u >> 16) & 1u)) >> 16);
}
__device__ __forceinline__ float bf16_tof(unsigned short b) {
    union { uint32_t u; float f; } c; c.u = ((uint32_t)b) << 16;
    return c.f;
}

// in-register 3-way truncation split of 8 f32 -> 3 bf16x8 planes
__device__ __forceinline__ void split3(const float4& a, const float4& b,
                                       s8v& h, s8v& m, s8v& l) {
    const float xe[8] = {a.x, a.y, a.z, a.w, b.x, b.y, b.z, b.w};
#pragma unroll
    for (int i = 0; i < 8; ++i) {
        union { float f; uint32_t u; } c; c.f = xe[i];
        h[i] = (short)(c.u >> 16);
        union { uint32_t u; float f; } t; t.u = c.u & 0xFFFF0000u;
        const float r1 = xe[i] - t.f;
        union { float f; uint32_t u; } c1; c1.f = r1;
        m[i] = (short)(c1.u >> 16);
        union { uint32_t u; float f; } t1; t1.u = c1.u & 0xFFFF0000u;
        const float r2 = r1 - t1.f;
        union { float f; uint32_t u; } c2; c2.f = r2;
        l[i] = (short)(c2.u >> 16);
    }
}

// async global->LDS DMA, 16 B per lane
__device__ __forceinline__ void gload16(const void* g, void* l) {
    __builtin_amdgcn_global_load_lds(
        (const __attribute__((address_space(1))) uint32_t*)g,
        (__attribute__((address_space(3))) uint32_t*)l, 16, 0, 0);
}

// ================= per-token noisy top-2 epilogue (shared) ==================
__device__ __forceinline__ void topk_epilogue(float g, float nl, float nz,
                                              int lane, size_t tg,
                                              float* __restrict__ out_probs,
                                              float* __restrict__ out_idx) {
    // softplus(z) = max(z,0) + log1p(exp(-|z|))
    const float sp = fmaxf(nl, 0.f) + log1pf(expf(-fabsf(nl)));
    const float noisy = g + nz * sp;

    float v = noisy;
    int idx = lane;
#pragma unroll
    for (int off = 32; off > 0; off >>= 1) {
        const float ov = __shfl_xor(v, off);
        const int oi = __shfl_xor(idx, off);
        if (ov > v || (ov == v && oi < idx)) { v = ov; idx = oi; }
    }
    const float v1 = v;
    const int i1 = idx;
    v = (lane == i1) ? -INFINITY : noisy;
    idx = lane;
#pragma unroll
    for (int off = 32; off > 0; off >>= 1) {
        const float ov = __shfl_xor(v, off);
        const int oi = __shfl_xor(idx, off);
        if (ov > v || (ov == v && oi < idx)) { v = ov; idx = oi; }
    }
    const float v2 = v;
    const int i2 = idx;

    const float e2 = expf(v2 - v1);
    const float denom = 1.f + e2;
    const float p = (lane == i1) ? (1.f / denom)
                                 : ((lane == i2) ? (e2 / denom) : 0.f);
    out_probs[tg * E_ + lane] = p;
    if (lane == 0) {
        out_idx[tg * 2 + 0] = (float)i1;
        out_idx[tg * 2 + 1] = (float)i2;
    }
}

// ---------------- kernel 1: pre-split W = [Wg;Wn] into 3 bf16 planes --------
// Frag-linear layout: plane p, n-frag f(8), k-step s(64), lane(64) -> 8 bf16.
// b-frag semantics: n = f*16 + (lane&15), k = s*32 + (lane>>4)*8 + i.
__global__ void w_split_kernel(const float* __restrict__ Wg,
                               const float* __restrict__ Wn,
                               unsigned short* __restrict__ wsp) {
    const int idx = blockIdx.x * blockDim.x + threadIdx.x;  // 0..32767
    const int lane = idx & 63;
    const int s = (idx >> 6) & 63;
    const int f = idx >> 12;
    const int n = f * 16 + (lane & 15);
    const int k0 = s * 32 + ((lane >> 4) << 3);
    const float* src = (n < 64) ? &Wg[(size_t)n * D_ + k0]
                                : &Wn[(size_t)(n - 64) * D_ + k0];
    s8v hv, mv, lv;
#pragma unroll
    for (int i = 0; i < 8; ++i) {
        const float f0 = src[i];
        const unsigned short hb = bf16_rne(f0);
        const float r1 = f0 - bf16_tof(hb);
        const unsigned short mb = bf16_rne(r1);
        const unsigned short lb = bf16_rne(r1 - bf16_tof(mb));
        hv[i] = (short)hb; mv[i] = (short)mb; lv[i] = (short)lb;
    }
    s8v* out = (s8v*)wsp;
    const int PLANE_FRAGS = 8 * 64 * 64;  // 32768 frags of 16 B per plane
    out[0 * PLANE_FRAGS + idx] = hv;
    out[1 * PLANE_FRAGS + idx] = mv;
    out[2 * PLANE_FRAGS + idx] = lv;
}

// ---------------- kernel 2: fused split-bf16 MFMA GEMM + noisy top-2 --------
// 512 threads = 8 waves (2m x 4n), BM=64, grid=256.
// Both A (f32 x-tile) and B (split-W frags) staged via async global_load_lds
// into double-buffered LDS; one barrier per K-tile (m97 pattern).
// A-reads use a both-sides XOR chunk swizzle (c ^ (row&7)) for bank spread.
__launch_bounds__(512)
__global__ void gemm_topk_kernel(const float* __restrict__ x,
                                 const unsigned short* __restrict__ wsp,
                                 const float* __restrict__ bg,
                                 const float* __restrict__ bn,
                                 const float* __restrict__ noise,
                                 float* __restrict__ out_probs,
                                 float* __restrict__ out_idx) {
    __shared__ __align__(16) char smem[2 * (ABUF_B + BBUF_B)];  // 64 KB
    char* smemA = smem;                       // 2 x 8 KB
    char* smemB = smem + 2 * ABUF_B;          // 2 x 24 KB
    const int tid = threadIdx.x;
    const int lane = tid & 63;
    const int wv = tid >> 6;           // 0..7
    const int wm = wv >> 2;            // 0..1 (m half: 32 rows)
    const int wn = wv & 3;             // 0..3 (n quadrant: 32 cols)
    const int block_m0 = blockIdx.x * BM;

    const int arow = lane & 15;
    const int akg = lane >> 4;
    const char* wb = (const char*)wsp;

    f4v acc00{}, acc01{}, acc10{}, acc11{};  // [mi][nf]

    // ---- DMA stage of K-tile t into buffer b ----
    // A: 64 rows x 128 B; thread tid covers chunk sidx=tid (row=tid>>3, c=tid&7).
    //    source chunk is pre-swizzled: global k-chunk = c ^ (row&7).
    // B: 24 frag-rows (p*8+f) x 1 KB; thread covers rows j*8+wv, j=0..2.
    const int sar = tid >> 3;          // A row this thread stages
    const int sac = tid & 7;           // A chunk slot
    const float* sasrc = x + (size_t)(block_m0 + sar) * D_ + ((sac ^ (sar & 7)) << 2);
    auto STAGE = [&](int t, int b) {
        gload16(sasrc + t * BK, smemA + b * ABUF_B + tid * 16);
#pragma unroll
        for (int j = 0; j < 3; ++j) {
            const int rf = j * 8 + wv;  // p = rf>>3, f = rf&7
            const char* src = wb + ((size_t)((rf >> 3) * 32768 + (rf & 7) * 4096
                                             + t * 64 + lane) * 16);
            gload16(src, smemB + b * BBUF_B + (rf * 64 + lane) * 16);
        }
    };

    auto COMPUTE = [&](int b) {
        const char* Ab = smemA + b * ABUF_B;
        const char* Bb = smemB + b * BBUF_B;
        s8v ah[2], am_[2], al[2];
#pragma unroll
        for (int mi = 0; mi < 2; ++mi) {
            const int r = wm * 32 + mi * 16 + arow;
            const int swz = r & 7;
            const float4 f0 = *(const float4*)(Ab + r * 128 + (((akg * 2 + 0) ^ swz) << 4));
            const float4 f1 = *(const float4*)(Ab + r * 128 + (((akg * 2 + 1) ^ swz) << 4));
            split3(f0, f1, ah[mi], am_[mi], al[mi]);
        }
        s8v bh[2], bm[2], bl[2];
#pragma unroll
        for (int nf = 0; nf < 2; ++nf) {
            const int f = wn * 2 + nf;
            bh[nf] = *(const s8v*)(Bb + ((0 * 8 + f) * 64 + lane) * 16);
            bm[nf] = *(const s8v*)(Bb + ((1 * 8 + f) * 64 + lane) * 16);
            bl[nf] = *(const s8v*)(Bb + ((2 * 8 + f) * 64 + lane) * 16);
        }
#define M4(A0, A1, B0, B1) \
        acc00 = __builtin_amdgcn_mfma_f32_16x16x32_bf16(A0, B0, acc00, 0, 0, 0); \
        acc01 = __builtin_amdgcn_mfma_f32_16x16x32_bf16(A0, B1, acc01, 0, 0, 0); \
        acc10 = __builtin_amdgcn_mfma_f32_16x16x32_bf16(A1, B0, acc10, 0, 0, 0); \
        acc11 = __builtin_amdgcn_mfma_f32_16x16x32_bf16(A1, B1, acc11, 0, 0, 0);
        M4(ah[0], ah[1], bh[0], bh[1])     // hi*hi
        M4(ah[0], ah[1], bm[0], bm[1])     // hi*mid
        M4(am_[0], am_[1], bh[0], bh[1])   // mid*hi
        M4(ah[0], ah[1], bl[0], bl[1])     // hi*lo
        M4(am_[0], am_[1], bm[0], bm[1])   // mid*mid
        M4(al[0], al[1], bh[0], bh[1])     // lo*hi
#undef M4
    };

    // ---- main loop: stage t+1 (async) || compute t; 1 barrier/tile ----
    STAGE(0, 0);
    __syncthreads();   // drains DMA(0)
    int cur = 0;
#pragma unroll 1
    for (int t = 0; t < KTILES; ++t) {
        if (t + 1 < KTILES) STAGE(t + 1, cur ^ 1);
        COMPUTE(cur);
        __syncthreads();   // implicit vmcnt(0): DMA(t+1) landed; buffers swap
        cur ^= 1;
    }

    // ---- epilogue: C tile to LDS (fp32), then per-token noisy top-2 ----
    float* Ct = (float*)smem;  // [64][CT_STRIDE] = 33792 B (reuses buffers)
    {
        const int ko4 = akg * 4;
        const f4v* accs[2][2] = {{&acc00, &acc01}, {&acc10, &acc11}};
#pragma unroll
        for (int mi = 0; mi < 2; ++mi)
#pragma unroll
            for (int ni = 0; ni < 2; ++ni) {
                const int col = wn * 32 + ni * 16 + arow;
#pragma unroll
                for (int r = 0; r < 4; ++r) {
                    const int row = wm * 32 + mi * 16 + ko4 + r;
                    Ct[row * CT_STRIDE + col] = (*accs[mi][ni])[r];
                }
            }
    }
    __syncthreads();

    const float my_bg = bg[lane];
    const float my_bn = bn[lane];
#pragma unroll 1
    for (int tt = 0; tt < 8; ++tt) {
        const int tl = wv * 8 + tt;
        const size_t tg = (size_t)block_m0 + tl;
        const float g = Ct[tl * CT_STRIDE + lane] + my_bg;
        const float nl = Ct[tl * CT_STRIDE + 64 + lane] + my_bn;
        const float nz = noise[tg * E_ + lane];
        topk_epilogue(g, nl, nz, lane, tg, out_probs, out_idx);
    }
}

// ---------------- fallback: pure-f32 fused kernel (no ws) -------------------
#define FBM 64
#define FBK 32
#define XS_STRIDE 68
#define WS_STRIDE 132
#define FCT_STRIDE 132

__launch_bounds__(256)
__global__ void noisy_topk_f32_kernel(const float* __restrict__ x,
                                      const float* __restrict__ Wg,
                                      const float* __restrict__ bg,
                                      const float* __restrict__ Wn,
                                      const float* __restrict__ bn,
                                      const float* __restrict__ noise,
                                      float* __restrict__ out_probs,
                                      float* __restrict__ out_idx) {
    __shared__ float smem[FBM * FCT_STRIDE];
    float* Xs = smem;
    float* Ws = smem + FBK * XS_STRIDE;

    const int tid = threadIdx.x;
    const int block_m0 = blockIdx.x * FBM;
    const int n0 = (tid & 31) * 4;
    const int m0 = (tid >> 5) * 8;

    float acc[8][4];
#pragma unroll
    for (int i = 0; i < 8; ++i)
#pragma unroll
        for (int j = 0; j < 4; ++j) acc[i][j] = 0.f;

    const int sj = tid & 7;
    const int sr = tid >> 3;

    for (int k0 = 0; k0 < D_; k0 += FBK) {
        __syncthreads();
#pragma unroll
        for (int it = 0; it < 2; ++it) {
            const int m = sr + it * 32;
            const float4 v = *reinterpret_cast<const float4*>(
                &x[(size_t)(block_m0 + m) * D_ + k0 + 4 * sj]);
            Xs[(4 * sj + 0) * XS_STRIDE + m] = v.x;
            Xs[(4 * sj + 1) * XS_STRIDE + m] = v.y;
            Xs[(4 * sj + 2) * XS_STRIDE + m] = v.z;
            Xs[(4 * sj + 3) * XS_STRIDE + m] = v.w;
        }
#pragma unroll
        for (int it = 0; it < 4; ++it) {
            const int n = sr + it * 32;
            const float* wrow = (n < 64) ? &Wg[(size_t)n * D_] : &Wn[(size_t)(n - 64) * D_];
            const float4 v = *reinterpret_cast<const float4*>(&wrow[k0 + 4 * sj]);
            Ws[(4 * sj + 0) * WS_STRIDE + n] = v.x;
            Ws[(4 * sj + 1) * WS_STRIDE + n] = v.y;
            Ws[(4 * sj + 2) * WS_STRIDE + n] = v.z;
            Ws[(4 * sj + 3) * WS_STRIDE + n] = v.w;
        }
        __syncthreads();
#pragma unroll
        for (int k = 0; k < FBK; ++k) {
            const float4 a0 = *reinterpret_cast<const float4*>(&Xs[k * XS_STRIDE + m0]);
            const float4 a1 = *reinterpret_cast<const float4*>(&Xs[k * XS_STRIDE + m0 + 4]);
            const float4 b4 = *reinterpret_cast<const float4*>(&Ws[k * WS_STRIDE + n0]);
            const float am[8] = {a0.x, a0.y, a0.z, a0.w, a1.x, a1.y, a1.z, a1.w};
            const float bb[4] = {b4.x, b4.y, b4.z, b4.w};
#pragma unroll
            for (int i = 0; i < 8; ++i)
#pragma unroll
                for (int j = 0; j < 4; ++j)
                    acc[i][j] = fmaf(am[i], bb[j], acc[i][j]);
        }
    }

    __syncthreads();
    float* Ct = smem;
#pragma unroll
    for (int i = 0; i < 8; ++i)
#pragma unroll
        for (int j = 0; j < 4; ++j)
            Ct[(m0 + i) * FCT_STRIDE + n0 + j] = acc[i][j];
    __syncthreads();

    const int wave = tid >> 6;
    const int lane = tid & 63;
    const float my_bg = bg[lane];
    const float my_bn = bn[lane];
#pragma unroll 1
    for (int tt = 0; tt < 16; ++tt) {
        const int tl = wave * 16 + tt;
        const size_t tg = (size_t)block_m0 + tl;
        const float g = Ct[tl * FCT_STRIDE + lane] + my_bg;
        const float nl = Ct[tl * FCT_STRIDE + 64 + lane] + my_bn;
        const float nz = noise[tg * E_ + lane];
        topk_epilogue(g, nl, nz, lane, tg, out_probs, out_idx);
    }
}

extern "C" void kernel_launch(void* const* d_in, const int* in_sizes, int n_in,
                              void* d_out, int out_size, void* d_ws, size_t ws_size,
                              hipStream_t stream) {
    const float* x = (const float*)d_in[0];
    const float* Wg = (const float*)d_in[1];
    const float* bg = (const float*)d_in[2];
    const float* Wn = (const float*)d_in[3];
    const float* bn = (const float*)d_in[4];
    const float* noise = (const float*)d_in[5];
    float* out_probs = (float*)d_out;
    float* out_idx = out_probs + (size_t)T_ * E_;

    const size_t WSP_BYTES = (size_t)3 * 32768 * 16;  // 1.57 MB
    if (ws_size >= WSP_BYTES) {
        unsigned short* wsp = (unsigned short*)d_ws;
        hipLaunchKernelGGL(w_split_kernel, dim3(128), dim3(256), 0, stream, Wg, Wn, wsp);
        hipLaunchKernelGGL(gemm_topk_kernel, dim3(T_ / BM), dim3(512), 0, stream,
                           x, wsp, bg, bn, noise, out_probs, out_idx);
    } else {
        hipLaunchKernelGGL(noisy_topk_f32_kernel, dim3(T_ / FBM), dim3(256), 0, stream,
                           x, Wg, bg, Wn, bn, noise, out_probs, out_idx);
    }
}

// Round 10
// 65.953 us; speedup vs baseline: 1.6963x; 1.3968x over previous
//
#include <hip/hip_runtime.h>
#include <math.h>
#include <stdint.h>

// NoisyTopKGating: B=4, S=4096, D=2048, E=64, K=2
#define D_ 2048
#define E_ 64
#define T_ 16384

#define BM 32                 // tokens per block
#define BK 32                 // k per tile
#define KTILES 64             // D_/BK
#define ABUF_B 4096           // 32 rows x 128 B (f32 x-tile)
#define BBUF_B 16384          // 16 frag-rows x 1024 B (2-plane f16 W tile)
#define BUF_B (ABUF_B + BBUF_B)   // 20480 per buffer
#define CT_STRIDE 132         // fp32 C tile stride (epilogue)

typedef _Float16 h8 __attribute__((ext_vector_type(8)));   // 8 f16 (4 VGPR)
typedef float f4v __attribute__((ext_vector_type(4)));     // MFMA acc

// in-register 2-plane f16 split: x = h + m/1024 (m scaled into normal range)
__device__ __forceinline__ void split2(const float4& a, const float4& b,
                                       h8& h, h8& m) {
    const float xe[8] = {a.x, a.y, a.z, a.w, b.x, b.y, b.z, b.w};
#pragma unroll
    for (int i = 0; i < 8; ++i) {
        const _Float16 hh_ = (_Float16)xe[i];              // v_cvt_f16_f32 (RNE)
        const float r = (xe[i] - (float)hh_) * 1024.0f;
        h[i] = hh_;
        m[i] = (_Float16)r;
    }
}

// async global->LDS DMA, 16 B per lane
__device__ __forceinline__ void gload16(const void* g, void* l) {
    __builtin_amdgcn_global_load_lds(
        (const __attribute__((address_space(1))) uint32_t*)g,
        (__attribute__((address_space(3))) uint32_t*)l, 16, 0, 0);
}

// ================= per-token noisy top-2 epilogue (shared) ==================
__device__ __forceinline__ void topk_epilogue(float g, float nl, float nz,
                                              int lane, size_t tg,
                                              float* __restrict__ out_probs,
                                              float* __restrict__ out_idx) {
    // softplus(z) = max(z,0) + log1p(exp(-|z|))
    const float sp = fmaxf(nl, 0.f) + log1pf(expf(-fabsf(nl)));
    const float noisy = g + nz * sp;

    float v = noisy;
    int idx = lane;
#pragma unroll
    for (int off = 32; off > 0; off >>= 1) {
        const float ov = __shfl_xor(v, off);
        const int oi = __shfl_xor(idx, off);
        if (ov > v || (ov == v && oi < idx)) { v = ov; idx = oi; }
    }
    const float v1 = v;
    const int i1 = idx;
    v = (lane == i1) ? -INFINITY : noisy;
    idx = lane;
#pragma unroll
    for (int off = 32; off > 0; off >>= 1) {
        const float ov = __shfl_xor(v, off);
        const int oi = __shfl_xor(idx, off);
        if (ov > v || (ov == v && oi < idx)) { v = ov; idx = oi; }
    }
    const float v2 = v;
    const int i2 = idx;

    const float e2 = expf(v2 - v1);
    const float denom = 1.f + e2;
    const float p = (lane == i1) ? (1.f / denom)
                                 : ((lane == i2) ? (e2 / denom) : 0.f);
    out_probs[tg * E_ + lane] = p;
    if (lane == 0) {
        out_idx[tg * 2 + 0] = (float)i1;
        out_idx[tg * 2 + 1] = (float)i2;
    }
}

// ---------------- kernel 1: pre-split W = [Wg;Wn] into 2 f16 planes --------
// Frag-linear layout: plane p (mid scaled x1024), frag f(8), k-step s(64),
// lane(64) -> 8 f16.  n = f*16 + (lane&15), k = s*32 + (lane>>4)*8 + i.
__global__ void w_split_kernel(const float* __restrict__ Wg,
                               const float* __restrict__ Wn,
                               h8* __restrict__ wsp) {
    const int idx = blockIdx.x * blockDim.x + threadIdx.x;  // 0..32767
    const int lane = idx & 63;
    const int s = (idx >> 6) & 63;
    const int f = idx >> 12;
    const int n = f * 16 + (lane & 15);
    const int k0 = s * 32 + ((lane >> 4) << 3);
    const float* src = (n < 64) ? &Wg[(size_t)n * D_ + k0]
                                : &Wn[(size_t)(n - 64) * D_ + k0];
    h8 hv, mv;
#pragma unroll
    for (int i = 0; i < 8; ++i) {
        const float w = src[i];
        const _Float16 wh = (_Float16)w;
        const float r = (w - (float)wh) * 1024.0f;
        hv[i] = wh;
        mv[i] = (_Float16)r;
    }
    wsp[0 * 32768 + idx] = hv;
    wsp[1 * 32768 + idx] = mv;
}

// ---------------- kernel 2: fused split-f16 MFMA GEMM + noisy top-2 --------
// BM=32, 512 threads = 8 waves (2m x 4n), grid=512 -> 2 blocks/CU.
// A (f32 x-tile, XOR-swizzled chunks) and B (2-plane f16 W frags) staged via
// async global_load_lds into double-buffered LDS; 1 barrier per K-tile.
// 4 scaled products in 4 acc chains: c = hh + (hm+mh)/1024 + mm/2^20.
__launch_bounds__(512)
__global__ void gemm_topk_kernel(const float* __restrict__ x,
                                 const h8* __restrict__ wsp,
                                 const float* __restrict__ bg,
                                 const float* __restrict__ bn,
                                 const float* __restrict__ noise,
                                 float* __restrict__ out_probs,
                                 float* __restrict__ out_idx) {
    __shared__ __align__(16) char smem[2 * BUF_B];  // 40960 B
    const int tid = threadIdx.x;
    const int lane = tid & 63;
    const int wv = tid >> 6;           // 0..7
    const int wm = wv >> 2;            // 0..1 (m half: 16 rows)
    const int wn = wv & 3;             // 0..3 (n quadrant: 32 cols)
    const int block_m0 = blockIdx.x * BM;

    const int arow = lane & 15;
    const int akg = lane >> 4;
    const char* wb = (const char*)wsp;

    f4v hh0{}, hh1{}, hm0{}, hm1{}, mh0{}, mh1{}, mm0{}, mm1{};

    // A staging: threads 0..255, row=tid>>3, chunk slot=tid&7; source chunk
    // pre-swizzled (c ^ (row&7)) so reads can XOR the same way (rule #21).
    const int sar = tid >> 3;
    const int sac = tid & 7;
    const float* sasrc = x + (size_t)(block_m0 + sar) * D_ + ((sac ^ (sar & 7)) << 2);
    // B staging: all 512 threads, 2 chunks each (plane j=0,1), frag=wv row.
    const int blv = lane;

    auto STAGE = [&](int t, int b) {
        char* base = smem + b * BUF_B;
        if (tid < 256)
            gload16(sasrc + t * BK, base + tid * 16);
        gload16(wb + ((size_t)(0 * 32768 + wv * 4096 + t * 64 + blv)) * 16,
                base + ABUF_B + ((0 * 8 + wv) * 64 + blv) * 16);
        gload16(wb + ((size_t)(1 * 32768 + wv * 4096 + t * 64 + blv)) * 16,
                base + ABUF_B + ((1 * 8 + wv) * 64 + blv) * 16);
    };

    auto COMPUTE = [&](int b) {
        const char* base = smem + b * BUF_B;
        const int r = wm * 16 + arow;
        const int swz = r & 7;
        const float4 f0 = *(const float4*)(base + r * 128 + (((akg * 2 + 0) ^ swz) << 4));
        const float4 f1 = *(const float4*)(base + r * 128 + (((akg * 2 + 1) ^ swz) << 4));
        h8 xh, xm;
        split2(f0, f1, xh, xm);
        const char* Bb = base + ABUF_B;
        const int fA = wn * 2, fB = wn * 2 + 1;
        const h8 bh0 = *(const h8*)(Bb + (fA * 64 + lane) * 16);
        const h8 bh1 = *(const h8*)(Bb + (fB * 64 + lane) * 16);
        const h8 bm0 = *(const h8*)(Bb + ((8 + fA) * 64 + lane) * 16);
        const h8 bm1 = *(const h8*)(Bb + ((8 + fB) * 64 + lane) * 16);
#define MF(A, B, C) C = __builtin_amdgcn_mfma_f32_16x16x32_f16(A, B, C, 0, 0, 0)
        MF(xh, bh0, hh0); MF(xh, bh1, hh1);
        MF(xh, bm0, hm0); MF(xh, bm1, hm1);
        MF(xm, bh0, mh0); MF(xm, bh1, mh1);
        MF(xm, bm0, mm0); MF(xm, bm1, mm1);
#undef MF
    };

    // ---- main loop: stage t+1 (async DMA) || compute t; 1 barrier/tile ----
    STAGE(0, 0);
    __syncthreads();
    int cur = 0;
#pragma unroll 1
    for (int t = 0; t < KTILES; ++t) {
        if (t + 1 < KTILES) STAGE(t + 1, cur ^ 1);
        COMPUTE(cur);
        __syncthreads();
        cur ^= 1;
    }

    // ---- epilogue: combine scaled acc chains, C to LDS, noisy top-2 ----
    float* Ct = (float*)smem;  // [32][CT_STRIDE] = 16896 B
    {
        const float S1 = 1.0f / 1024.0f;
        const float S2 = S1 * S1;
        const int ko4 = akg * 4;
#pragma unroll
        for (int r = 0; r < 4; ++r) {
            const int row = wm * 16 + ko4 + r;
            const int col0 = (wn * 2 + 0) * 16 + arow;
            const int col1 = (wn * 2 + 1) * 16 + arow;
            Ct[row * CT_STRIDE + col0] = hh0[r] + (hm0[r] + mh0[r]) * S1 + mm0[r] * S2;
            Ct[row * CT_STRIDE + col1] = hh1[r] + (hm1[r] + mh1[r]) * S1 + mm1[r] * S2;
        }
    }
    __syncthreads();

    const float my_bg = bg[lane];
    const float my_bn = bn[lane];
#pragma unroll 1
    for (int tt = 0; tt < 4; ++tt) {
        const int tl = wv * 4 + tt;
        const size_t tg = (size_t)block_m0 + tl;
        const float g = Ct[tl * CT_STRIDE + lane] + my_bg;
        const float nl = Ct[tl * CT_STRIDE + 64 + lane] + my_bn;
        const float nz = noise[tg * E_ + lane];
        topk_epilogue(g, nl, nz, lane, tg, out_probs, out_idx);
    }
}

// ---------------- fallback: pure-f32 fused kernel (no ws) -------------------
#define FBM 64
#define FBK 32
#define XS_STRIDE 68
#define WS_STRIDE 132
#define FCT_STRIDE 132

__launch_bounds__(256)
__global__ void noisy_topk_f32_kernel(const float* __restrict__ x,
                                      const float* __restrict__ Wg,
                                      const float* __restrict__ bg,
                                      const float* __restrict__ Wn,
                                      const float* __restrict__ bn,
                                      const float* __restrict__ noise,
                                      float* __restrict__ out_probs,
                                      float* __restrict__ out_idx) {
    __shared__ float smem[FBM * FCT_STRIDE];
    float* Xs = smem;
    float* Ws = smem + FBK * XS_STRIDE;

    const int tid = threadIdx.x;
    const int block_m0 = blockIdx.x * FBM;
    const int n0 = (tid & 31) * 4;
    const int m0 = (tid >> 5) * 8;

    float acc[8][4];
#pragma unroll
    for (int i = 0; i < 8; ++i)
#pragma unroll
        for (int j = 0; j < 4; ++j) acc[i][j] = 0.f;

    const int sj = tid & 7;
    const int sr = tid >> 3;

    for (int k0 = 0; k0 < D_; k0 += FBK) {
        __syncthreads();
#pragma unroll
        for (int it = 0; it < 2; ++it) {
            const int m = sr + it * 32;
            const float4 v = *reinterpret_cast<const float4*>(
                &x[(size_t)(block_m0 + m) * D_ + k0 + 4 * sj]);
            Xs[(4 * sj + 0) * XS_STRIDE + m] = v.x;
            Xs[(4 * sj + 1) * XS_STRIDE + m] = v.y;
            Xs[(4 * sj + 2) * XS_STRIDE + m] = v.z;
            Xs[(4 * sj + 3) * XS_STRIDE + m] = v.w;
        }
#pragma unroll
        for (int it = 0; it < 4; ++it) {
            const int n = sr + it * 32;
            const float* wrow = (n < 64) ? &Wg[(size_t)n * D_] : &Wn[(size_t)(n - 64) * D_];
            const float4 v = *reinterpret_cast<const float4*>(&wrow[k0 + 4 * sj]);
            Ws[(4 * sj + 0) * WS_STRIDE + n] = v.x;
            Ws[(4 * sj + 1) * WS_STRIDE + n] = v.y;
            Ws[(4 * sj + 2) * WS_STRIDE + n] = v.z;
            Ws[(4 * sj + 3) * WS_STRIDE + n] = v.w;
        }
        __syncthreads();
#pragma unroll
        for (int k = 0; k < FBK; ++k) {
            const float4 a0 = *reinterpret_cast<const float4*>(&Xs[k * XS_STRIDE + m0]);
            const float4 a1 = *reinterpret_cast<const float4*>(&Xs[k * XS_STRIDE + m0 + 4]);
            const float4 b4 = *reinterpret_cast<const float4*>(&Ws[k * WS_STRIDE + n0]);
            const float am[8] = {a0.x, a0.y, a0.z, a0.w, a1.x, a1.y, a1.z, a1.w};
            const float bb[4] = {b4.x, b4.y, b4.z, b4.w};
#pragma unroll
            for (int i = 0; i < 8; ++i)
#pragma unroll
                for (int j = 0; j < 4; ++j)
                    acc[i][j] = fmaf(am[i], bb[j], acc[i][j]);
        }
    }

    __syncthreads();
    float* Ct = smem;
#pragma unroll
    for (int i = 0; i < 8; ++i)
#pragma unroll
        for (int j = 0; j < 4; ++j)
            Ct[(m0 + i) * FCT_STRIDE + n0 + j] = acc[i][j];
    __syncthreads();

    const int wave = tid >> 6;
    const int lane = tid & 63;
    const float my_bg = bg[lane];
    const float my_bn = bn[lane];
#pragma unroll 1
    for (int tt = 0; tt < 16; ++tt) {
        const int tl = wave * 16 + tt;
        const size_t tg = (size_t)block_m0 + tl;
        const float g = Ct[tl * FCT_STRIDE + lane] + my_bg;
        const float nl = Ct[tl * FCT_STRIDE + 64 + lane] + my_bn;
        const float nz = noise[tg * E_ + lane];
        topk_epilogue(g, nl, nz, lane, tg, out_probs, out_idx);
    }
}

extern "C" void kernel_launch(void* const* d_in, const int* in_sizes, int n_in,
                              void* d_out, int out_size, void* d_ws, size_t ws_size,
                              hipStream_t stream) {
    const float* x = (const float*)d_in[0];
    const float* Wg = (const float*)d_in[1];
    const float* bg = (const float*)d_in[2];
    const float* Wn = (const float*)d_in[3];
    const float* bn = (const float*)d_in[4];
    const float* noise = (const float*)d_in[5];
    float* out_probs = (float*)d_out;
    float* out_idx = out_probs + (size_t)T_ * E_;

    const size_t WSP_BYTES = (size_t)2 * 32768 * 16;  // 1.0 MB
    if (ws_size >= WSP_BYTES) {
        h8* wsp = (h8*)d_ws;
        hipLaunchKernelGGL(w_split_kernel, dim3(128), dim3(256), 0, stream, Wg, Wn, wsp);
        hipLaunchKernelGGL(gemm_topk_kernel, dim3(T_ / BM), dim3(512), 0, stream,
                           x, wsp, bg, bn, noise, out_probs, out_idx);
    } else {
        hipLaunchKernelGGL(noisy_topk_f32_kernel, dim3(T_ / FBM), dim3(256), 0, stream,
                           x, Wg, bg, Wn, bn, noise, out_probs, out_idx);
    }
}